// Round 1
// baseline (170.796 us; speedup 1.0000x reference)
//
#include <hip/hip_runtime.h>

// SSIM fused kernel for [16,1,1024,1024] fp32 images, 11-tap Gaussian (win passed in).
// Vertical blur in per-thread register ring; horizontal blur via per-row LDS buffer.
// Deterministic reduction: per-block partials in d_ws, finalize kernel -> d_out[0].

#define W      1024
#define H      1024
#define NIMG   16
#define WS     11
#define HALO   5
#define BX     128
#define OUTX   (BX - 2 * HALO)            // 118 output cols per block
#define ROWS   121                        // 11*11 -> clean unroll-by-11
#define GX     ((W + OUTX - 1) / OUTX)    // 9
#define GY     ((H + ROWS - 1) / ROWS)    // 9
#define NBLK   (GX * GY * NIMG)           // 1296

__global__ __launch_bounds__(BX) void ssim_main(const float* __restrict__ img1,
                                                const float* __restrict__ img2,
                                                const float* __restrict__ win,
                                                float* __restrict__ partials)
{
    __shared__ float2 sAB[BX];   // (v1,  v2)
    __shared__ float2 sCD[BX];   // (v11, v22)
    __shared__ float  sE [BX];   // (v12)

    const int tid = threadIdx.x;
    const int n   = blockIdx.z;
    const int c0  = blockIdx.x * OUTX;
    const int col = c0 + tid - HALO;      // this thread's input column
    const int r0  = blockIdx.y * ROWS;

    const bool colOK = (col >= 0) && (col < W);
    const float* __restrict__ p1 = img1 + (size_t)n * (size_t)(W * H);
    const float* __restrict__ p2 = img2 + (size_t)n * (size_t)(W * H);

    float w[WS];
#pragma unroll
    for (int k = 0; k < WS; ++k) w[k] = win[k];

    // register ring buffer of raw input rows (zero-padded)
    float a[WS], b[WS];
#pragma unroll
    for (int k = 0; k < WS - 1; ++k) {
        const int j  = r0 - HALO + k;
        const bool ok = colOK && (j >= 0) && (j < H);
        a[k + 1] = ok ? p1[(size_t)j * W + col] : 0.0f;
        b[k + 1] = ok ? p2[(size_t)j * W + col] : 0.0f;
    }

    const bool outThread = (tid >= HALO) && (tid < HALO + OUTX) && (col < W);

    float tsum = 0.0f;

#pragma unroll 11
    for (int rr = 0; rr < ROWS; ++rr) {
        const int r = r0 + rr;

        // shift ring (copies dissolve under unroll)
#pragma unroll
        for (int k = 0; k < WS - 1; ++k) { a[k] = a[k + 1]; b[k] = b[k + 1]; }
        {
            const int j   = r + HALO;
            const bool ok = colOK && (j < H);
            a[WS - 1] = ok ? p1[(size_t)j * W + col] : 0.0f;
            b[WS - 1] = ok ? p2[(size_t)j * W + col] : 0.0f;
        }

        // vertical blur of 5 channels
        float v1 = 0.f, v2 = 0.f, v11 = 0.f, v22 = 0.f, v12 = 0.f;
#pragma unroll
        for (int k = 0; k < WS; ++k) {
            const float av = a[k], bv = b[k], wk = w[k];
            v1  = fmaf(wk, av,      v1);
            v2  = fmaf(wk, bv,      v2);
            v11 = fmaf(wk, av * av, v11);
            v22 = fmaf(wk, bv * bv, v22);
            v12 = fmaf(wk, av * bv, v12);
        }

        __syncthreads();                      // protect prior iteration's readers
        sAB[tid] = make_float2(v1,  v2);
        sCD[tid] = make_float2(v11, v22);
        sE [tid] = v12;
        __syncthreads();

        if (outThread && (r < H)) {
            float m1 = 0.f, m2 = 0.f, x11 = 0.f, x22 = 0.f, x12 = 0.f;
#pragma unroll
            for (int k = 0; k < WS; ++k) {
                const float  wk = w[k];
                const float2 ab = sAB[tid - HALO + k];
                const float2 cd = sCD[tid - HALO + k];
                const float  e  = sE [tid - HALO + k];
                m1  = fmaf(wk, ab.x, m1);
                m2  = fmaf(wk, ab.y, m2);
                x11 = fmaf(wk, cd.x, x11);
                x22 = fmaf(wk, cd.y, x22);
                x12 = fmaf(wk, e,    x12);
            }
            const float mu1s = m1 * m1, mu2s = m2 * m2, mu12 = m1 * m2;
            const float s1  = x11 - mu1s;
            const float s2  = x22 - mu2s;
            const float s12 = x12 - mu12;
            const float C1f = 0.0001f;        // 0.01^2
            const float C2f = 0.0009f;        // 0.03^2
            const float num = (2.0f * mu12 + C1f) * (2.0f * s12 + C2f);
            const float den = (mu1s + mu2s + C1f) * (s1 + s2 + C2f);
            tsum += num / den;
        }
    }

    // block reduction (2 waves of 64)
#pragma unroll
    for (int off = 32; off > 0; off >>= 1)
        tsum += __shfl_down(tsum, off, 64);

    __shared__ float wsum[BX / 64];
    if ((tid & 63) == 0) wsum[tid >> 6] = tsum;
    __syncthreads();
    if (tid == 0) {
        const float s = wsum[0] + wsum[1];
        partials[(blockIdx.z * GY + blockIdx.y) * GX + blockIdx.x] = s;
    }
}

__global__ __launch_bounds__(256) void ssim_finalize(const float* __restrict__ partials,
                                                     float* __restrict__ out)
{
    double s = 0.0;
    for (int i = threadIdx.x; i < NBLK; i += 256) s += (double)partials[i];
#pragma unroll
    for (int off = 32; off > 0; off >>= 1)
        s += __shfl_down(s, off, 64);

    __shared__ double ws[4];
    if ((threadIdx.x & 63) == 0) ws[threadIdx.x >> 6] = s;
    __syncthreads();
    if (threadIdx.x == 0) {
        const double t = ws[0] + ws[1] + ws[2] + ws[3];
        out[0] = (float)(t / (double)((size_t)NIMG * W * H));
    }
}

extern "C" void kernel_launch(void* const* d_in, const int* in_sizes, int n_in,
                              void* d_out, int out_size, void* d_ws, size_t ws_size,
                              hipStream_t stream)
{
    const float* img1 = (const float*)d_in[0];
    const float* img2 = (const float*)d_in[1];
    const float* win  = (const float*)d_in[2];
    float* partials   = (float*)d_ws;
    float* out        = (float*)d_out;

    dim3 grid(GX, GY, NIMG);
    dim3 block(BX);
    ssim_main<<<grid, block, 0, stream>>>(img1, img2, win, partials);
    ssim_finalize<<<1, 256, 0, stream>>>(partials, out);
}

// Round 2
// 119.676 us; speedup vs baseline: 1.4272x; 1.4272x over previous
//
#include <hip/hip_runtime.h>

// SSIM fused kernel: [16,1,1024,1024] fp32, 11-tap separable Gaussian.
// Vertical blur in per-thread register ring; horizontal via double-buffered
// LDS row buffer (1 barrier/row). Interior blocks take a check-free path.
// Deterministic two-stage reduction -> d_out[0].

#define W      1024
#define H      1024
#define NIMG   16
#define WS     11
#define HALO   5
#define BX     128
#define OUTX   (BX - 2 * HALO)            // 118 output cols per block
#define ROWS   44                         // output rows per block
#define GX     ((W + OUTX - 1) / OUTX)    // 9
#define GY     ((H + ROWS - 1) / ROWS)    // 24
#define NBLK   (GX * GY * NIMG)           // 3456

template<bool INT>
__device__ __forceinline__ float tile_loop(const float* __restrict__ p1,
                                           const float* __restrict__ p2,
                                           const float* __restrict__ w,
                                           int col, int r0, int tid,
                                           float2 (*sAB)[BX],
                                           float2 (*sCD)[BX],
                                           float  (*sE)[BX])
{
    const bool colOK = INT || ((col >= 0) && (col < W));

    // register ring of raw input rows (zero-padded outside image)
    float a[WS], b[WS];
#pragma unroll
    for (int k = 0; k < WS - 1; ++k) {
        const int j  = r0 - HALO + k;
        const bool ok = INT || (colOK && (j >= 0) && (j < H));
        a[k + 1] = ok ? p1[(size_t)j * W + col] : 0.0f;
        b[k + 1] = ok ? p2[(size_t)j * W + col] : 0.0f;
    }

    const bool outThread = (tid >= HALO) && (tid < HALO + OUTX) && (INT || (col < W));

    float tsum = 0.0f;

#pragma unroll 11
    for (int rr = 0; rr < ROWS; ++rr) {
        // shift ring (dissolves under unroll)
#pragma unroll
        for (int k = 0; k < WS - 1; ++k) { a[k] = a[k + 1]; b[k] = b[k + 1]; }
        {
            const int j   = r0 + rr + HALO;
            const bool ok = INT || (colOK && (j < H));
            a[WS - 1] = ok ? p1[(size_t)j * W + col] : 0.0f;
            b[WS - 1] = ok ? p2[(size_t)j * W + col] : 0.0f;
        }

        // vertical blur of 5 channels
        float v1 = 0.f, v2 = 0.f, v11 = 0.f, v22 = 0.f, v12 = 0.f;
#pragma unroll
        for (int k = 0; k < WS; ++k) {
            const float av = a[k], bv = b[k], wk = w[k];
            v1  = fmaf(wk, av,      v1);
            v2  = fmaf(wk, bv,      v2);
            v11 = fmaf(wk, av * av, v11);
            v22 = fmaf(wk, bv * bv, v22);
            v12 = fmaf(wk, av * bv, v12);
        }

        const int buf = rr & 1;
        sAB[buf][tid] = make_float2(v1,  v2);
        sCD[buf][tid] = make_float2(v11, v22);
        sE [buf][tid] = v12;
        __syncthreads();

        if (outThread && (INT || (r0 + rr < H))) {
            float m1 = 0.f, m2 = 0.f, x11 = 0.f, x22 = 0.f, x12 = 0.f;
#pragma unroll
            for (int k = 0; k < WS; ++k) {
                const float  wk = w[k];
                const float2 ab = sAB[buf][tid - HALO + k];
                const float2 cd = sCD[buf][tid - HALO + k];
                const float  e  = sE [buf][tid - HALO + k];
                m1  = fmaf(wk, ab.x, m1);
                m2  = fmaf(wk, ab.y, m2);
                x11 = fmaf(wk, cd.x, x11);
                x22 = fmaf(wk, cd.y, x22);
                x12 = fmaf(wk, e,    x12);
            }
            const float mu1s = m1 * m1, mu2s = m2 * m2, mu12 = m1 * m2;
            const float s1  = x11 - mu1s;
            const float s2  = x22 - mu2s;
            const float s12 = x12 - mu12;
            const float C1f = 0.0001f;        // 0.01^2
            const float C2f = 0.0009f;        // 0.03^2
            const float num = (2.0f * mu12 + C1f) * (2.0f * s12 + C2f);
            const float den = (mu1s + mu2s + C1f) * (s1 + s2 + C2f);
            tsum += num / den;
        }
    }
    return tsum;
}

__global__ __launch_bounds__(BX) void ssim_main(const float* __restrict__ img1,
                                                const float* __restrict__ img2,
                                                const float* __restrict__ win,
                                                float* __restrict__ partials)
{
    __shared__ float2 sAB[2][BX];
    __shared__ float2 sCD[2][BX];
    __shared__ float  sE [2][BX];

    const int tid = threadIdx.x;
    const int n   = blockIdx.z;
    const int c0  = blockIdx.x * OUTX;
    const int col = c0 + tid - HALO;
    const int r0  = blockIdx.y * ROWS;

    const float* __restrict__ p1 = img1 + (size_t)n * (size_t)(W * H);
    const float* __restrict__ p2 = img2 + (size_t)n * (size_t)(W * H);

    float w[WS];
#pragma unroll
    for (int k = 0; k < WS; ++k) w[k] = win[k];

    const bool interior = (c0 >= HALO) && (c0 + BX - HALO <= W) &&
                          (r0 >= HALO) && (r0 + ROWS + HALO <= H);

    float tsum;
    if (interior) tsum = tile_loop<true >(p1, p2, w, col, r0, tid, sAB, sCD, sE);
    else          tsum = tile_loop<false>(p1, p2, w, col, r0, tid, sAB, sCD, sE);

    // block reduction (2 waves of 64)
#pragma unroll
    for (int off = 32; off > 0; off >>= 1)
        tsum += __shfl_down(tsum, off, 64);

    __shared__ float wsum[BX / 64];
    if ((tid & 63) == 0) wsum[tid >> 6] = tsum;
    __syncthreads();
    if (tid == 0) {
        const float s = wsum[0] + wsum[1];
        partials[((size_t)n * GY + blockIdx.y) * GX + blockIdx.x] = s;
    }
}

__global__ __launch_bounds__(256) void ssim_finalize(const float* __restrict__ partials,
                                                     float* __restrict__ out)
{
    double s = 0.0;
    for (int i = threadIdx.x; i < NBLK; i += 256) s += (double)partials[i];
#pragma unroll
    for (int off = 32; off > 0; off >>= 1)
        s += __shfl_down(s, off, 64);

    __shared__ double ws[4];
    if ((threadIdx.x & 63) == 0) ws[threadIdx.x >> 6] = s;
    __syncthreads();
    if (threadIdx.x == 0) {
        const double t = ws[0] + ws[1] + ws[2] + ws[3];
        out[0] = (float)(t / (double)((size_t)NIMG * W * H));
    }
}

extern "C" void kernel_launch(void* const* d_in, const int* in_sizes, int n_in,
                              void* d_out, int out_size, void* d_ws, size_t ws_size,
                              hipStream_t stream)
{
    const float* img1 = (const float*)d_in[0];
    const float* img2 = (const float*)d_in[1];
    const float* win  = (const float*)d_in[2];
    float* partials   = (float*)d_ws;
    float* out        = (float*)d_out;

    dim3 grid(GX, GY, NIMG);
    dim3 block(BX);
    ssim_main<<<grid, block, 0, stream>>>(img1, img2, win, partials);
    ssim_finalize<<<1, 256, 0, stream>>>(partials, out);
}